// Round 1
// baseline (285.217 us; speedup 1.0000x reference)
//
#include <hip/hip_runtime.h>

// ---------- types ----------
typedef __attribute__((ext_vector_type(8))) short short8;
typedef __attribute__((ext_vector_type(8), may_alias)) short short8a;
typedef __attribute__((ext_vector_type(4))) short short4a_ __attribute__((may_alias));
typedef __attribute__((ext_vector_type(2), may_alias)) short short2a;
typedef __attribute__((ext_vector_type(4))) float float4_;
typedef __attribute__((ext_vector_type(4), may_alias)) float float4a;
typedef __attribute__((ext_vector_type(2), may_alias)) float float2a;

__device__ __forceinline__ float b2f(short h) {
  unsigned int u = ((unsigned int)(unsigned short)h) << 16;
  return __builtin_bit_cast(float, u);
}
__device__ __forceinline__ short f2b(float f) {
  unsigned int u = __builtin_bit_cast(unsigned int, f);
  u += 0x7fffu + ((u >> 16) & 1u);   // RNE
  return (short)(unsigned short)(u >> 16);
}

#define GLOBAL_AS __attribute__((address_space(1)))
#define LDS_AS    __attribute__((address_space(3)))
__device__ __forceinline__ void async_copy16(void* lds, const void* g) {
  __builtin_amdgcn_global_load_lds((GLOBAL_AS const void*)g, (LDS_AS void*)lds, 16, 0, 0);
}

// ---------- 1. fused prep: x->bf16, Wq|Wk|Wv transpose (q-scale folded), Wo transpose, rope table ----------
// grid: [0,1536) wqkv tiles, [1536,2560) wo tiles, [2560,10752) cvt blocks, [10752,11008) rope table
__global__ __launch_bounds__(256) void prep(const float* __restrict__ x,
                                            const float* __restrict__ Wq,
                                            const float* __restrict__ Wk,
                                            const float* __restrict__ Wv,
                                            const float* __restrict__ Wo,
                                            short* __restrict__ xb,
                                            short* __restrict__ wqkvt,
                                            short* __restrict__ wot,
                                            float* __restrict__ rtab) {
  __shared__ float tile[64][65];
  int bid = blockIdx.x;
  if (bid < 1536) {                     // Wq|Wk|Wv -> [3072][2048] bf16 (B^T)
    int k0 = (bid & 31) * 64, n0 = (bid >> 5) * 64;
    for (int idx = threadIdx.x; idx < 4096; idx += 256) {
      int r = idx >> 6, cc = idx & 63;
      int n = n0 + cc;
      float v;
      if (n < 2048)      v = Wq[(size_t)(k0 + r) * 2048 + n] * 0.08838834764831845f; // fold 1/sqrt(128)
      else if (n < 2560) v = Wk[(size_t)(k0 + r) * 512 + (n - 2048)];
      else               v = Wv[(size_t)(k0 + r) * 512 + (n - 2560)];
      tile[r][cc] = v;
    }
    __syncthreads();
    for (int idx = threadIdx.x; idx < 4096; idx += 256) {
      int r = idx >> 6, cc = idx & 63;
      wqkvt[(size_t)(n0 + r) * 2048 + k0 + cc] = f2b(tile[cc][r]);
    }
  } else if (bid < 2560) {              // Wo -> [2048][2048] bf16 (B^T)
    int t = bid - 1536;
    int k0 = (t & 31) * 64, n0 = (t >> 5) * 64;
    for (int idx = threadIdx.x; idx < 4096; idx += 256) {
      int r = idx >> 6, cc = idx & 63;
      tile[r][cc] = Wo[(size_t)(k0 + r) * 2048 + n0 + cc];
    }
    __syncthreads();
    for (int idx = threadIdx.x; idx < 4096; idx += 256) {
      int r = idx >> 6, cc = idx & 63;
      wot[(size_t)(n0 + r) * 2048 + k0 + cc] = f2b(tile[cc][r]);
    }
  } else if (bid < 10752) {             // x fp32 -> bf16
    int i = (bid - 2560) * 256 + threadIdx.x;
    float4a v = ((const float4a*)x)[i];
    short4a_ o;
    o.x = f2b(v.x); o.y = f2b(v.y); o.z = f2b(v.z); o.w = f2b(v.w);
    ((short4a_*)xb)[i] = o;
  } else {                              // rope table: rtab[(pos*64+i)*2] = {cos, sin}
    int idx = (bid - 10752) * 256 + threadIdx.x;   // 0..65535
    int pos = idx >> 6, i = idx & 63;
    float inv = exp2f((float)i * -0.20762050593478f);  // 10000^(-2i/128)
    float s, c;
    sincosf((float)pos * inv, &s, &c);
    float2a cs; cs.x = c; cs.y = s;
    ((float2a*)rtab)[idx] = cs;
  }
}

// ---------- 2. GEMM  C[M][N] = A[M][K] * B^T[N][K] ----------
// 256x256 tile, BK=64, 8 waves (2M x 4N, 128x64 per wave), 8-phase counted-vmcnt schedule.
// LDS: 2 buffers x (A 256x64 + B 256x64) bf16 = 128 KiB. Each K-tile split into two
// K-halves (kh0: k 0..31, kh1: k 32..63); staging unit = one {A|B} x kh = 16 KB =
// 2 x global_load_lds(16B)/thread. Chunk swizzle: 16B-chunk' = chunk ^ ((row>>1)&3)
// (pre-swizzled global source, linear LDS dest; read applies the same XOR -> 2-way = free).
// Schedule per tile t (phases A..D = (kk,mhalf)): stage SA(t+1,kh1), SB(t+1,kh1),
// SA(t+2,kh0), SB(t+2,kh0); one s_waitcnt vmcnt(4) at end of tile (allows exactly the
// two newest half-tiles, = t+2's kh0 pair, to remain in flight). Never vmcnt(0) mid-loop.
// MODE 0: fp32 direct store. MODE 1: n0<2560 -> fused RoPE -> qkv; else transposed V -> vt.
#define FENCE() __builtin_amdgcn_sched_barrier(0)
#define WAITV(N) asm volatile("s_waitcnt vmcnt(" #N ")" ::: "memory")
#define WAIT_TAIL(C) do { if (C) WAITV(4); else WAITV(0); } while (0)

#define STAGE_A(TP, TKK, ST)                                                   \
  do {                                                                         \
    if ((ST) < nK) {                                                           \
      short* d_ = &lsm[(TP) * 32768 + (TKK) * 8192 + wave * 512];              \
      const short* s_ = Asrc + (size_t)(ST) * 64 + (TKK) * 32;                 \
      async_copy16(d_, s_);                                                    \
      async_copy16(d_ + 4096, s_ + 128 * (size_t)K);                           \
    }                                                                          \
  } while (0)
#define STAGE_B(TP, TKK, ST)                                                   \
  do {                                                                         \
    if ((ST) < nK) {                                                           \
      short* d_ = &lsm[(TP) * 32768 + 16384 + (TKK) * 8192 + wave * 512];      \
      const short* s_ = Bsrc + (size_t)(ST) * 64 + (TKK) * 32;                 \
      async_copy16(d_, s_);                                                    \
      async_copy16(d_ + 4096, s_ + 128 * (size_t)K);                           \
    }                                                                          \
  } while (0)

#define PHASE(P, KK, MH, STAGE_STMT, WAIT_STMT)                                \
  do {                                                                         \
    short8 af[4];                                                              \
    _Pragma("unroll") for (int mt = 0; mt < 4; ++mt)                           \
        af[mt] = *(const short8a*)&lsm[(P) * 32768 + (KK) * 8192 +             \
                                       aoff[(MH) * 4 + mt]];                   \
    if ((MH) == 0) {                                                           \
      _Pragma("unroll") for (int nt = 0; nt < 4; ++nt)                         \
          bf[nt] = *(const short8a*)&lsm[(P) * 32768 + 16384 + (KK) * 8192 +   \
                                         boff[nt]];                            \
    }                                                                          \
    STAGE_STMT;                                                                \
    FENCE();                                                                   \
    __builtin_amdgcn_s_barrier();                                              \
    FENCE();                                                                   \
    __builtin_amdgcn_s_setprio(1);                                             \
    _Pragma("unroll") for (int mt = 0; mt < 4; ++mt)                           \
        _Pragma("unroll") for (int nt = 0; nt < 4; ++nt)                       \
            acc[(MH) * 4 + mt][nt] = __builtin_amdgcn_mfma_f32_16x16x32_bf16(  \
                af[mt], bf[nt], acc[(MH) * 4 + mt][nt], 0, 0, 0);              \
    __builtin_amdgcn_s_setprio(0);                                             \
    FENCE();                                                                   \
    WAIT_STMT;                                                                 \
    __builtin_amdgcn_s_barrier();                                              \
    FENCE();                                                                   \
  } while (0)

template <int MODE>
__global__ __launch_bounds__(512, 2)
void gemm_bt(const short* __restrict__ A, const short* __restrict__ B,
             void* __restrict__ Cv, const float* __restrict__ rtab,
             short* __restrict__ vt, int M, int N, int K) {
  __shared__ alignas(16) short lsm[65536];   // 128 KiB
  const int tid = threadIdx.x;
  const int wave = tid >> 6, lane = tid & 63;
  const int quad = lane >> 4, l16 = lane & 15;
  const int m0 = blockIdx.x * 256, n0 = blockIdx.y * 256;
  const int wm = (wave >> 2) * 128, wn = (wave & 3) * 64;
  const int nK = K >> 6;                      // must be even, >= 2

  // thread-constant LDS fragment offsets (shorts), swizzle folded in
  int aoff[8], boff[4];
#pragma unroll
  for (int mt = 0; mt < 8; ++mt) {
    int r = wm + mt * 16 + l16;
    aoff[mt] = r * 32 + (quad ^ ((r >> 1) & 3)) * 8;
  }
#pragma unroll
  for (int nt = 0; nt < 4; ++nt) {
    int r = wn + nt * 16 + l16;
    boff[nt] = r * 32 + (quad ^ ((r >> 1) & 3)) * 8;
  }
  // staging: thread ti -> LDS (row ti>>2, chunk ti&3); holds global chunk (ti&3)^((row>>1)&3)
  const int r0 = tid >> 2;
  const int qq = (tid & 3) ^ ((r0 >> 1) & 3);   // same for row r0 and r0+128 (128>>1 % 4 == 0)
  const short* Asrc = A + (size_t)(m0 + r0) * K + qq * 8;
  const short* Bsrc = B + (size_t)(n0 + r0) * K + qq * 8;

  float4_ acc[8][4];
#pragma unroll
  for (int i = 0; i < 8; i++)
#pragma unroll
    for (int j = 0; j < 4; j++) acc[i][j] = (float4_){0.f, 0.f, 0.f, 0.f};
  short8 bf[4];

  // prologue: tile0 all 4 units + tile1 kh0 pair, then retire tile0 (allow tile1 kh0 in flight)
  STAGE_A(0, 0, 0); STAGE_B(0, 0, 0); STAGE_A(0, 1, 0); STAGE_B(0, 1, 0);
  STAGE_A(1, 0, 1); STAGE_B(1, 0, 1);
  FENCE();
  if (nK > 1) WAITV(4); else WAITV(0);
  __builtin_amdgcn_s_barrier();
  FENCE();

  for (int t = 0; t < nK; t += 2) {
    // tile t (parity 0)
    PHASE(0, 0, 0, STAGE_A(1, 1, t + 1), );
    PHASE(0, 0, 1, STAGE_B(1, 1, t + 1), );
    PHASE(0, 1, 0, STAGE_A(0, 0, t + 2), );
    PHASE(0, 1, 1, STAGE_B(0, 0, t + 2), WAIT_TAIL(t + 2 < nK));
    // tile t+1 (parity 1)
    PHASE(1, 0, 0, STAGE_A(0, 1, t + 2), );
    PHASE(1, 0, 1, STAGE_B(0, 1, t + 2), );
    PHASE(1, 1, 0, STAGE_A(1, 0, t + 3), );
    PHASE(1, 1, 1, STAGE_B(1, 0, t + 3), WAIT_TAIL(t + 3 < nK));
  }

  if (MODE == 1) {
    const bool isRope = (n0 < 2560);          // block-uniform; tile regions align (Q:8,K:2,V:2 tiles)
    short* lC = lsm;                          // [128][264] bf16, two 128-row passes
    const int posBase = m0 & 1023;
    short* Cb = (short*)Cv;
#pragma unroll
    for (int ph = 0; ph < 2; ++ph) {
      __syncthreads();                        // pass-(ph-1) reads / staging reads done
      if ((wave >> 2) == ph) {                // waves owning these 128 rows write their acc
#pragma unroll
        for (int mt = 0; mt < 8; ++mt)
#pragma unroll
          for (int nt = 0; nt < 4; ++nt)
#pragma unroll
            for (int r = 0; r < 4; r++)
              lC[(mt * 16 + quad * 4 + r) * 264 + wn + nt * 16 + l16] = f2b(acc[mt][nt][r]);
      }
      __syncthreads();
      if (isRope) {
        // 128 rows x 2 heads x 32 col-pairs = 8192 items
#pragma unroll
        for (int it = 0; it < 16; ++it) {
          int idx = it * 512 + tid;
          int row = idx >> 6;                 // local row 0..127
          int grow = ph * 128 + row;
          int head = (idx >> 5) & 1;
          int c2 = (idx & 31) * 2;            // freq pair c2, c2+1 (in [0,64))
          int col = head * 128 + c2;
          float4a t = *(const float4a*)&rtab[((size_t)(posBase + grow) * 64 + c2) * 2];
          short2a t1 = *(const short2a*)&lC[row * 264 + col];
          short2a t2 = *(const short2a*)&lC[row * 264 + col + 64];
          float t1a = b2f(t1.x), t1b = b2f(t1.y);
          float t2a = b2f(t2.x), t2b = b2f(t2.y);
          short2a o1, o2;
          o1.x = f2b(t1a * t.x - t2a * t.y); o1.y = f2b(t1b * t.z - t2b * t.w);
          o2.x = f2b(t2a * t.x + t1a * t.y); o2.y = f2b(t2b * t.z + t1b * t.w);
          size_t base = (size_t)(m0 + grow) * N + n0 + col;
          *(short2a*)&Cb[base] = o1;
          *(short2a*)&Cb[base + 64] = o2;
        }
      } else {
        // V block: transposed store into vt[(b*4+kv)*128+d][seq]; tile spans 2 kv heads
        const int bkvBase = (m0 >> 10) * 4;
        const int nrel = n0 - 2560;           // 0 or 256
#pragma unroll
        for (int it = 0; it < 8; ++it) {
          int idx = it * 512 + tid;           // 256 d x 16 jc
          int d = idx >> 4;
          int jc = idx & 15;                  // 8-row chunk within this 128-row pass
          int gcol = nrel + d;
          int kvh = gcol >> 7, dd = gcol & 127;
          short8 v;
#pragma unroll
          for (int k = 0; k < 8; ++k) v[k] = lC[(jc * 8 + k) * 264 + d];
          *(short8a*)&vt[(size_t)((bkvBase + kvh) * 128 + dd) * 1024 + posBase + ph * 128 + jc * 8] = v;
        }
      }
    }
  } else {
    float* Cf = (float*)Cv;
#pragma unroll
    for (int mt = 0; mt < 8; ++mt)
#pragma unroll
      for (int nt = 0; nt < 4; ++nt) {
        int row = m0 + wm + mt * 16 + quad * 4;
        int col = n0 + wn + nt * 16 + l16;
        float4_ v = acc[mt][nt];
#pragma unroll
        for (int r = 0; r < 4; r++) Cf[(size_t)(row + r) * N + col] = v[r];
      }
  }
}

// ---------- 3. GQA causal flash attention (no-max softmax; 128-row Q tiles) ----------
// grid (64 = b*16+h, 8 qtiles reversed), 256 threads = 4 waves x (2 groups x 16 q-rows)
__global__ __launch_bounds__(256, 2)
void flash(const short* __restrict__ qkv, const short* __restrict__ vt,
           const float* __restrict__ head_scale, short* __restrict__ attn) {
  __shared__ alignas(16) short lK[64 * 128];   // [krow][d-chunk swizzled]
  __shared__ alignas(16) short lV[128 * 64];   // [d][krow-chunk swizzled]
  __shared__ alignas(16) short lP[4][32 * 72]; // per-wave P (32 rows), padded stride 72
  const int tid = threadIdx.x, wave = tid >> 6, lane = tid & 63;
  const int quad = lane >> 4, l16 = lane & 15;
  const int bh = blockIdx.x, b = bh >> 4, h = bh & 15, kv = h >> 2;
  const int qt = 7 - blockIdx.y;               // heavy blocks first
  const int base_w = qt * 128 + wave * 32;     // wave's first q-row
  short8 qf[2][4];
#pragma unroll
  for (int g = 0; g < 2; g++) {
    int qrow = base_w + g * 16 + l16;
    const short* qp = qkv + (size_t)(b * 1024 + qrow) * 3072 + h * 128;
#pragma unroll
    for (int kc = 0; kc < 4; kc++) qf[g][kc] = *(const short8a*)(qp + kc * 32 + quad * 8);
  }
  float4_ O[2][8];
#pragma unroll
  for (int g = 0; g < 2; g++)
#pragma unroll
    for (int i = 0; i < 8; i++) O[g][i] = (float4_){0.f, 0.f, 0.f, 0.f};
  float rsacc[2][4] = {{0.f, 0.f, 0.f, 0.f}, {0.f, 0.f, 0.f, 0.f}};
  const size_t kbase = (size_t)(b * 1024) * 3072 + 2048 + kv * 128;
  const size_t vbase = (size_t)((b * 4 + kv) * 128) * 1024;
  const int slot16 = lane & 15, rr4 = lane >> 4;
  const int slot8 = lane & 7, dr8 = lane >> 3;
  const int nkt = 2 * qt + 2;
  for (int kt = 0; kt < nkt; ++kt) {
    __syncthreads();
#pragma unroll
    for (int cc = 0; cc < 4; ++cc) {           // K tile: 64 rows x 128 d
      int rb = wave * 16 + cc * 4;
      int r = rb + rr4;
      int c = slot16 ^ (r & 15);
      async_copy16(&lK[rb * 128], qkv + kbase + (size_t)(kt * 64 + r) * 3072 + c * 8);
    }
#pragma unroll
    for (int cc = 0; cc < 4; ++cc) {           // V tile: 128 d x 64 rows
      int db = wave * 32 + cc * 8;
      int d = db + dr8;
      int c = slot8 ^ (d & 7);
      async_copy16(&lV[db * 64], vt + vbase + (size_t)d * 1024 + kt * 64 + c * 8);
    }
    __syncthreads();
    if (kt * 64 > base_w + 31) continue;       // wave fully below diagonal (uniform)
    // S = Q K^T, both groups share kf
    float4_ S[2][4];
#pragma unroll
    for (int st = 0; st < 4; ++st) {
      float4_ s0 = (float4_){0.f, 0.f, 0.f, 0.f}, s1 = s0;
      int kr = st * 16 + l16;
#pragma unroll
      for (int kc = 0; kc < 4; ++kc) {
        int c = kc * 4 + quad;
        short8 kf = *(const short8a*)&lK[kr * 128 + (c ^ (kr & 15)) * 8];
        s0 = __builtin_amdgcn_mfma_f32_16x16x32_bf16(qf[0][kc], kf, s0, 0, 0, 0);
        s1 = __builtin_amdgcn_mfma_f32_16x16x32_bf16(qf[1][kc], kf, s1, 0, 0, 0);
      }
      S[0][st] = s0; S[1][st] = s1;
    }
    // causal mask + exp + P store
#pragma unroll
    for (int g = 0; g < 2; g++) {
      int gbase = base_w + g * 16;
      if (kt * 64 + 63 > gbase) {
#pragma unroll
        for (int st = 0; st < 4; ++st)
#pragma unroll
          for (int r = 0; r < 4; r++)
            if (kt * 64 + st * 16 + l16 > gbase + quad * 4 + r) S[g][st][r] = -1e30f;
      }
#pragma unroll
      for (int st = 0; st < 4; ++st)
#pragma unroll
        for (int r = 0; r < 4; r++) {
          float pv = __expf(S[g][st][r]);
          rsacc[g][r] += pv;
          lP[wave][(g * 16 + quad * 4 + r) * 72 + st * 16 + l16] = f2b(pv);
        }
    }
    short8 pf[2][2];
#pragma unroll
    for (int g = 0; g < 2; g++)
#pragma unroll
      for (int kc2 = 0; kc2 < 2; kc2++)
        pf[g][kc2] = *(const short8a*)&lP[wave][(g * 16 + l16) * 72 + kc2 * 32 + quad * 8];
#pragma unroll
    for (int dt = 0; dt < 8; ++dt) {
      int d = dt * 16 + l16;
#pragma unroll
      for (int kc2 = 0; kc2 < 2; kc2++) {
        int c = kc2 * 4 + quad;
        short8 vf = *(const short8a*)&lV[d * 64 + (c ^ (d & 7)) * 8];
        O[0][dt] = __builtin_amdgcn_mfma_f32_16x16x32_bf16(pf[0][kc2], vf, O[0][dt], 0, 0, 0);
        O[1][dt] = __builtin_amdgcn_mfma_f32_16x16x32_bf16(pf[1][kc2], vf, O[1][dt], 0, 0, 0);
      }
    }
  }
  float hs = head_scale[h];
#pragma unroll
  for (int g = 0; g < 2; g++) {
    float l_i[4];
#pragma unroll
    for (int r = 0; r < 4; r++) {
      float rs = rsacc[g][r];
#pragma unroll
      for (int off = 8; off; off >>= 1) rs += __shfl_xor(rs, off, 64);
      l_i[r] = rs;
    }
    int qrow = base_w + g * 16 + quad * 4;
#pragma unroll
    for (int dt = 0; dt < 8; ++dt) {
      int col = h * 128 + dt * 16 + l16;
#pragma unroll
      for (int r = 0; r < 4; r++) {
        float o = O[g][dt][r] * (hs / l_i[r]);
        attn[(size_t)(b * 1024 + qrow + r) * 2048 + col] = f2b(o);
      }
    }
  }
}

// ---------- launch ----------
extern "C" void kernel_launch(void* const* d_in, const int* in_sizes, int n_in,
                              void* d_out, int out_size, void* d_ws, size_t ws_size,
                              hipStream_t stream) {
  const float* x  = (const float*)d_in[0];
  const float* Wq = (const float*)d_in[1];
  const float* Wk = (const float*)d_in[2];
  const float* Wv = (const float*)d_in[3];
  const float* Wo = (const float*)d_in[4];
  const float* hs = (const float*)d_in[5];
  float* out = (float*)d_out;
  char* ws = (char*)d_ws;
  // ws layout (64 MB total)
  short* xb    = (short*)(ws);                  // 16 MB  [4096][2048]   (reused as attn)
  short* wqkvt = (short*)(ws + 16777216);       // 12 MB  [3072][2048]
  short* wot   = (short*)(ws + 29360128);       //  8 MB  [2048][2048]
  short* qkv   = (short*)(ws + 37748736);       // 24 MB  [4096][3072] (V cols unused)
  short* vt    = (short*)(ws + 62914560);       //  4 MB  [2048][1024]
  short* attn  = xb;                            // alias: xb dead after GEMM1
  // rope table lives in d_out's tail: d_out (32 MB fp32) is dead until GEMM2 fully overwrites it
  float* rtab  = out + 8257536;                 // 512 KB = 131072 floats

  prep<<<11008, 256, 0, stream>>>(x, Wq, Wk, Wv, Wo, xb, wqkvt, wot, rtab);
  gemm_bt<1><<<dim3(16, 12), 512, 0, stream>>>(xb, wqkvt, (void*)qkv, rtab, vt, 4096, 3072, 2048);
  flash<<<dim3(64, 8), 256, 0, stream>>>(qkv, vt, hs, attn);
  gemm_bt<0><<<dim3(16, 8), 512, 0, stream>>>(attn, wot, (void*)out, nullptr, nullptr, 4096, 2048, 2048);
}

// Round 2
// 250.339 us; speedup vs baseline: 1.1393x; 1.1393x over previous
//
#include <hip/hip_runtime.h>

// ---------- types ----------
typedef __attribute__((ext_vector_type(8))) short short8;
typedef __attribute__((ext_vector_type(8), may_alias)) short short8a;
typedef __attribute__((ext_vector_type(4))) short short4a_ __attribute__((may_alias));
typedef __attribute__((ext_vector_type(2), may_alias)) short short2a;
typedef __attribute__((ext_vector_type(4))) float float4_;
typedef __attribute__((ext_vector_type(4), may_alias)) float float4a;
typedef __attribute__((ext_vector_type(2), may_alias)) float float2a;

__device__ __forceinline__ float b2f(short h) {
  unsigned int u = ((unsigned int)(unsigned short)h) << 16;
  return __builtin_bit_cast(float, u);
}
__device__ __forceinline__ short f2b(float f) {
  unsigned int u = __builtin_bit_cast(unsigned int, f);
  u += 0x7fffu + ((u >> 16) & 1u);   // RNE
  return (short)(unsigned short)(u >> 16);
}

#define GLOBAL_AS __attribute__((address_space(1)))
#define LDS_AS    __attribute__((address_space(3)))
__device__ __forceinline__ void async_copy16(void* lds, const void* g) {
  __builtin_amdgcn_global_load_lds((GLOBAL_AS const void*)g, (LDS_AS void*)lds, 16, 0, 0);
}

// ---------- 1. fused prep: x->bf16, Wq|Wk|Wv transpose (q-scale folded), Wo transpose, rope table ----------
__global__ __launch_bounds__(256) void prep(const float* __restrict__ x,
                                            const float* __restrict__ Wq,
                                            const float* __restrict__ Wk,
                                            const float* __restrict__ Wv,
                                            const float* __restrict__ Wo,
                                            short* __restrict__ xb,
                                            short* __restrict__ wqkvt,
                                            short* __restrict__ wot,
                                            float* __restrict__ rtab) {
  __shared__ float tile[64][65];
  int bid = blockIdx.x;
  if (bid < 1536) {                     // Wq|Wk|Wv -> [3072][2048] bf16 (B^T)
    int k0 = (bid & 31) * 64, n0 = (bid >> 5) * 64;
    for (int idx = threadIdx.x; idx < 4096; idx += 256) {
      int r = idx >> 6, cc = idx & 63;
      int n = n0 + cc;
      float v;
      if (n < 2048)      v = Wq[(size_t)(k0 + r) * 2048 + n] * 0.08838834764831845f; // fold 1/sqrt(128)
      else if (n < 2560) v = Wk[(size_t)(k0 + r) * 512 + (n - 2048)];
      else               v = Wv[(size_t)(k0 + r) * 512 + (n - 2560)];
      tile[r][cc] = v;
    }
    __syncthreads();
    for (int idx = threadIdx.x; idx < 4096; idx += 256) {
      int r = idx >> 6, cc = idx & 63;
      wqkvt[(size_t)(n0 + r) * 2048 + k0 + cc] = f2b(tile[cc][r]);
    }
  } else if (bid < 2560) {              // Wo -> [2048][2048] bf16 (B^T)
    int t = bid - 1536;
    int k0 = (t & 31) * 64, n0 = (t >> 5) * 64;
    for (int idx = threadIdx.x; idx < 4096; idx += 256) {
      int r = idx >> 6, cc = idx & 63;
      tile[r][cc] = Wo[(size_t)(k0 + r) * 2048 + n0 + cc];
    }
    __syncthreads();
    for (int idx = threadIdx.x; idx < 4096; idx += 256) {
      int r = idx >> 6, cc = idx & 63;
      wot[(size_t)(n0 + r) * 2048 + k0 + cc] = f2b(tile[cc][r]);
    }
  } else if (bid < 10752) {             // x fp32 -> bf16
    int i = (bid - 2560) * 256 + threadIdx.x;
    float4a v = ((const float4a*)x)[i];
    short4a_ o;
    o.x = f2b(v.x); o.y = f2b(v.y); o.z = f2b(v.z); o.w = f2b(v.w);
    ((short4a_*)xb)[i] = o;
  } else {                              // rope table: rtab[(pos*64+i)*2] = {cos, sin}
    int idx = (bid - 10752) * 256 + threadIdx.x;   // 0..65535
    int pos = idx >> 6, i = idx & 63;
    float inv = exp2f((float)i * -0.20762050593478f);  // 10000^(-2i/128)
    float s, c;
    sincosf((float)pos * inv, &s, &c);
    float2a cs; cs.x = c; cs.y = s;
    ((float2a*)rtab)[idx] = cs;
  }
}

// ---------- 2. GEMM  C[M][N] = A[M][K] * B^T[N][K] ----------
// BM=128 x BN(384|256), BK=64, 8 waves (2M x 4N; per-wave 64 x BN/4), 100% grid fill.
// Consumption groups g = (tile,kh): kh halves of BK. Stage group g+3 during group g;
// at each group end wait vmcnt(2*LPG) => the group needed next was issued 3 groups
// (~6 phases, ~900cy) earlier and 2 groups stay in flight. Never vmcnt(0) mid-loop.
// (Round-1 bug: vmcnt(4) also waited for a group issued 2 phases earlier -> drain0-like.)
// LDS per buffer: [A kh0 8K][A kh1 8K][B kh0][B kh1], chunk swizzle chunk^((row>>1)&3)
// via pre-swizzled global source (linear LDS dest), read applies same XOR (2-way = free).
// MODE 0: fp32 direct store. MODE 1: per-head epilogue (head<20 rope -> qkv, else V^T -> vt).
#define FENCE() __builtin_amdgcn_sched_barrier(0)

template <int N_>
__device__ __forceinline__ void waitv() {
  if constexpr (N_ == 8)      asm volatile("s_waitcnt vmcnt(8)" ::: "memory");
  else if constexpr (N_ == 6) asm volatile("s_waitcnt vmcnt(6)" ::: "memory");
  else if constexpr (N_ == 4) asm volatile("s_waitcnt vmcnt(4)" ::: "memory");
  else if constexpr (N_ == 3) asm volatile("s_waitcnt vmcnt(3)" ::: "memory");
  else                        asm volatile("s_waitcnt vmcnt(0)" ::: "memory");
}

// stage group (T_,KH_) into parity P_; part 0 = A + B.slab0 (2 loads), part 1 = B.slab1(+2) 
#define STG(P_, KH_, T_, PART_)                                                    \
  do { if ((T_) < nK) {                                                            \
    const size_t co_ = (size_t)(T_) * 64 + (KH_) * 32;                             \
    if ((PART_) == 0) {                                                            \
      async_copy16(&lsm[(P_) * BUFSZ + (KH_) * 4096 + wave * 512], Asrc + co_);    \
      async_copy16(&lsm[(P_) * BUFSZ + 8192 + (KH_) * BBUF + wave * 512],          \
                   Bsrc + co_);                                                    \
    } else {                                                                       \
      async_copy16(&lsm[(P_) * BUFSZ + 8192 + (KH_) * BBUF + 4096 + wave * 512],   \
                   Bsrc + 128 * (size_t)K + co_);                                  \
      if (BSLAB == 3)                                                              \
        async_copy16(&lsm[(P_) * BUFSZ + 8192 + (KH_) * BBUF + 8192 + wave * 512], \
                     Bsrc + 256 * (size_t)K + co_);                                \
    }                                                                              \
  } } while (0)

#define WAITG(G_)                                                                  \
  do { int rem_ = 2 * nK - 2 - (G_);                                               \
    if (rem_ >= 2) waitv<2 * LPG>();                                               \
    else if (rem_ == 1) waitv<LPG>();                                              \
    else waitv<0>(); } while (0)

// 8-phase body (BN=384): phase = (group, m-half), 12 MFMA/phase, bf held across the pair
#define PHASE8(P_, KK_, MH_, STAGE_STMT, ENDW)                                     \
  {                                                                                \
    short8 af[2];                                                                  \
    _Pragma("unroll") for (int mi = 0; mi < 2; ++mi)                               \
      af[mi] = *(const short8a*)&lsm[(P_) * BUFSZ + (KK_) * 4096 +                 \
                                     aoff[(MH_) * 2 + mi]];                        \
    if ((MH_) == 0) {                                                              \
      _Pragma("unroll") for (int ni = 0; ni < NF; ++ni)                            \
        bf[ni] = *(const short8a*)&lsm[(P_) * BUFSZ + 8192 + (KK_) * BBUF +        \
                                       boff[ni]];                                  \
    }                                                                              \
    STAGE_STMT;                                                                    \
    FENCE();                                                                       \
    __builtin_amdgcn_s_barrier();                                                  \
    FENCE();                                                                       \
    __builtin_amdgcn_s_setprio(1);                                                 \
    _Pragma("unroll") for (int mi = 0; mi < 2; ++mi)                               \
      _Pragma("unroll") for (int ni = 0; ni < NF; ++ni)                            \
        acc[(MH_) * 2 + mi][ni] = __builtin_amdgcn_mfma_f32_16x16x32_bf16(         \
            af[mi], bf[ni], acc[(MH_) * 2 + mi][ni], 0, 0, 0);                     \
    __builtin_amdgcn_s_setprio(0);                                                 \
    FENCE();                                                                       \
    ENDW;                                                                          \
    __builtin_amdgcn_s_barrier();                                                  \
    FENCE();                                                                       \
  }

// 4-phase body (BN=256): phase = group, 16 MFMA/phase
#define PHASE4(P_, KK_, STAGE0, STAGE1, ENDW)                                      \
  {                                                                                \
    short8 af[4];                                                                  \
    _Pragma("unroll") for (int mi = 0; mi < 4; ++mi)                               \
      af[mi] = *(const short8a*)&lsm[(P_) * BUFSZ + (KK_) * 4096 + aoff[mi]];      \
    short8 bf[4];                                                                  \
    _Pragma("unroll") for (int ni = 0; ni < 4; ++ni)                               \
      bf[ni] = *(const short8a*)&lsm[(P_) * BUFSZ + 8192 + (KK_) * BBUF +          \
                                     boff[ni]];                                    \
    STAGE0; STAGE1;                                                                \
    FENCE();                                                                       \
    __builtin_amdgcn_s_barrier();                                                  \
    FENCE();                                                                       \
    __builtin_amdgcn_s_setprio(1);                                                 \
    _Pragma("unroll") for (int mi = 0; mi < 4; ++mi)                               \
      _Pragma("unroll") for (int ni = 0; ni < 4; ++ni)                             \
        acc[mi][ni] = __builtin_amdgcn_mfma_f32_16x16x32_bf16(                     \
            af[mi], bf[ni], acc[mi][ni], 0, 0, 0);                                 \
    __builtin_amdgcn_s_setprio(0);                                                 \
    FENCE();                                                                       \
    ENDW;                                                                          \
    __builtin_amdgcn_s_barrier();                                                  \
    FENCE();                                                                       \
  }

template <int MODE, int BN>
__global__ __launch_bounds__(512, 2)
void gemm_bt(const short* __restrict__ A, const short* __restrict__ B,
             void* __restrict__ Cv, const float* __restrict__ rtab,
             short* __restrict__ vt, int M, int N, int K) {
  constexpr int NF = BN / 64;          // n-frags per wave (6 | 4)
  constexpr int BSLAB = BN / 128;      // B 128-row slabs (3 | 2)
  constexpr int LPG = 1 + BSLAB;       // staging loads per group per thread (4 | 3)
  constexpr int BBUF = BSLAB * 4096;   // shorts per B kh-slab
  constexpr int BUFSZ = 8192 + 2 * BBUF;
  __shared__ alignas(16) short lsm[2 * BUFSZ];   // 128 KiB | 96 KiB
  const int tid = threadIdx.x;
  const int wave = tid >> 6, lane = tid & 63;
  const int quad = lane >> 4, l16 = lane & 15;
  const int m0 = blockIdx.x * 128, n0 = blockIdx.y * BN;
  const int wm = (wave >> 2) * 64, wn = (wave & 3) * (BN / 4);
  const int nK = K >> 6;               // even, >= 2

  // thread-constant LDS fragment offsets (shorts), swizzle folded in
  int aoff[4], boff[NF];
#pragma unroll
  for (int j = 0; j < 4; ++j) {
    int r = wm + j * 16 + l16;
    aoff[j] = r * 32 + (quad ^ ((r >> 1) & 3)) * 8;
  }
#pragma unroll
  for (int ni = 0; ni < NF; ++ni) {
    int r = wn + ni * 16 + l16;
    boff[ni] = r * 32 + (quad ^ ((r >> 1) & 3)) * 8;
  }
  // staging: thread ti -> LDS (row ti>>2, chunk ti&3); holds global chunk (ti&3)^((row>>1)&3)
  const int r0 = tid >> 2;
  const int qq = (tid & 3) ^ ((r0 >> 1) & 3);   // invariant under row+128/+256
  const short* Asrc = A + (size_t)(m0 + r0) * K + qq * 8;
  const short* Bsrc = B + (size_t)(n0 + r0) * K + qq * 8;

  float4_ acc[4][NF];
#pragma unroll
  for (int i = 0; i < 4; i++)
#pragma unroll
    for (int j = 0; j < NF; j++) acc[i][j] = (float4_){0.f, 0.f, 0.f, 0.f};

  // prologue: stage groups 0,1,2; retire group 0 (keep 1,2 in flight)
  STG(0, 0, 0, 0); STG(0, 0, 0, 1);
  STG(0, 1, 0, 0); STG(0, 1, 0, 1);
  STG(1, 0, 1, 0); STG(1, 0, 1, 1);
  FENCE();
  waitv<2 * LPG>();
  __builtin_amdgcn_s_barrier();
  FENCE();

  if constexpr (BN == 384) {
    short8 bf[NF];
    for (int t = 0; t < nK; t += 2) {
      PHASE8(0, 0, 0, STG(1, 1, t + 1, 0), );
      PHASE8(0, 0, 1, STG(1, 1, t + 1, 1), WAITG(2 * t));
      PHASE8(0, 1, 0, STG(0, 0, t + 2, 0), );
      PHASE8(0, 1, 1, STG(0, 0, t + 2, 1), WAITG(2 * t + 1));
      PHASE8(1, 0, 0, STG(0, 1, t + 2, 0), );
      PHASE8(1, 0, 1, STG(0, 1, t + 2, 1), WAITG(2 * t + 2));
      PHASE8(1, 1, 0, STG(1, 0, t + 3, 0), );
      PHASE8(1, 1, 1, STG(1, 0, t + 3, 1), WAITG(2 * t + 3));
    }
  } else {
    for (int t = 0; t < nK; t += 2) {
      PHASE4(0, 0, STG(1, 1, t + 1, 0), STG(1, 1, t + 1, 1), WAITG(2 * t));
      PHASE4(0, 1, STG(0, 0, t + 2, 0), STG(0, 0, t + 2, 1), WAITG(2 * t + 1));
      PHASE4(1, 0, STG(0, 1, t + 2, 0), STG(0, 1, t + 2, 1), WAITG(2 * t + 2));
      PHASE4(1, 1, STG(1, 0, t + 3, 0), STG(1, 0, t + 3, 1), WAITG(2 * t + 3));
    }
  }

  if (MODE == 1) {
    constexpr int LCS = BN + 4;               // 388: 8-row stride -> bank+16 (2-way free)
    short* lC = lsm;                          // [128][LCS] bf16, single pass
    const int posBase = m0 & 1023;
    short* Cb = (short*)Cv;
    __syncthreads();
#pragma unroll
    for (int mt = 0; mt < 4; ++mt)
#pragma unroll
      for (int ni = 0; ni < NF; ++ni)
#pragma unroll
        for (int r = 0; r < 4; r++)
          lC[(wm + mt * 16 + quad * 4 + r) * LCS + wn + ni * 16 + l16] = f2b(acc[mt][ni][r]);
    __syncthreads();
    const int hb = n0 >> 7;                   // 3 heads per tile; head<20 rope, else V
#pragma unroll
    for (int hh = 0; hh < 3; ++hh) {
      const int H = hb + hh;
      if (H < 20) {                           // rope: 128 rows x 32 col-pair groups
        for (int it = 0; it < 8; ++it) {
          int idx = it * 512 + tid;
          int row = idx >> 5;
          int c2 = (idx & 31) * 2;            // pair (c2, c2+64)
          float4a tt = *(const float4a*)&rtab[((size_t)(posBase + row) * 64 + c2) * 2];
          short2a t1 = *(const short2a*)&lC[row * LCS + hh * 128 + c2];
          short2a t2 = *(const short2a*)&lC[row * LCS + hh * 128 + c2 + 64];
          float t1a = b2f(t1.x), t1b = b2f(t1.y);
          float t2a = b2f(t2.x), t2b = b2f(t2.y);
          short2a o1, o2;
          o1.x = f2b(t1a * tt.x - t2a * tt.y); o1.y = f2b(t1b * tt.z - t2b * tt.w);
          o2.x = f2b(t2a * tt.x + t1a * tt.y); o2.y = f2b(t2b * tt.z + t1b * tt.w);
          size_t base = (size_t)(m0 + row) * N + n0 + hh * 128;
          *(short2a*)&Cb[base + c2] = o1;
          *(short2a*)&Cb[base + c2 + 64] = o2;
        }
      } else {                                // V head: transpose into vt[(b*4+hv)*128+d][seq]
        const int hv = H - 20;
        const int bb = m0 >> 10;
        for (int it = 0; it < 4; ++it) {
          int idx = it * 512 + tid;           // 128 d x 16 jc
          int d = idx >> 4, jc = idx & 15;
          short8 v;
#pragma unroll
          for (int k = 0; k < 8; ++k) v[k] = lC[(jc * 8 + k) * LCS + hh * 128 + d];
          *(short8a*)&vt[(size_t)((bb * 4 + hv) * 128 + d) * 1024 + posBase + jc * 8] = v;
        }
      }
    }
  } else {
    float* Cf = (float*)Cv;
#pragma unroll
    for (int mt = 0; mt < 4; ++mt)
#pragma unroll
      for (int ni = 0; ni < NF; ++ni) {
        int row = m0 + wm + mt * 16 + quad * 4;
        int col = n0 + wn + ni * 16 + l16;
        float4_ v = acc[mt][ni];
#pragma unroll
        for (int r = 0; r < 4; r++) Cf[(size_t)(row + r) * N + col] = v[r];
      }
  }
}

// ---------- 3. GQA causal flash attention (no-max softmax; 128-row Q tiles) ----------
// grid (64 = b*16+h, 8 qtiles reversed), 256 threads = 4 waves x (2 groups x 16 q-rows)
__global__ __launch_bounds__(256, 2)
void flash(const short* __restrict__ qkv, const short* __restrict__ vt,
           const float* __restrict__ head_scale, short* __restrict__ attn) {
  __shared__ alignas(16) short lK[64 * 128];   // [krow][d-chunk swizzled]
  __shared__ alignas(16) short lV[128 * 64];   // [d][krow-chunk swizzled]
  __shared__ alignas(16) short lP[4][32 * 72]; // per-wave P (32 rows), padded stride 72
  const int tid = threadIdx.x, wave = tid >> 6, lane = tid & 63;
  const int quad = lane >> 4, l16 = lane & 15;
  const int bh = blockIdx.x, b = bh >> 4, h = bh & 15, kv = h >> 2;
  const int qt = 7 - blockIdx.y;               // heavy blocks first
  const int base_w = qt * 128 + wave * 32;     // wave's first q-row
  short8 qf[2][4];
#pragma unroll
  for (int g = 0; g < 2; g++) {
    int qrow = base_w + g * 16 + l16;
    const short* qp = qkv + (size_t)(b * 1024 + qrow) * 3072 + h * 128;
#pragma unroll
    for (int kc = 0; kc < 4; kc++) qf[g][kc] = *(const short8a*)(qp + kc * 32 + quad * 8);
  }
  float4_ O[2][8];
#pragma unroll
  for (int g = 0; g < 2; g++)
#pragma unroll
    for (int i = 0; i < 8; i++) O[g][i] = (float4_){0.f, 0.f, 0.f, 0.f};
  float rsacc[2][4] = {{0.f, 0.f, 0.f, 0.f}, {0.f, 0.f, 0.f, 0.f}};
  const size_t kbase = (size_t)(b * 1024) * 3072 + 2048 + kv * 128;
  const size_t vbase = (size_t)((b * 4 + kv) * 128) * 1024;
  const int slot16 = lane & 15, rr4 = lane >> 4;
  const int slot8 = lane & 7, dr8 = lane >> 3;
  const int nkt = 2 * qt + 2;
  for (int kt = 0; kt < nkt; ++kt) {
    __syncthreads();
#pragma unroll
    for (int cc = 0; cc < 4; ++cc) {           // K tile: 64 rows x 128 d
      int rb = wave * 16 + cc * 4;
      int r = rb + rr4;
      int c = slot16 ^ (r & 15);
      async_copy16(&lK[rb * 128], qkv + kbase + (size_t)(kt * 64 + r) * 3072 + c * 8);
    }
#pragma unroll
    for (int cc = 0; cc < 4; ++cc) {           // V tile: 128 d x 64 rows
      int db = wave * 32 + cc * 8;
      int d = db + dr8;
      int c = slot8 ^ (d & 7);
      async_copy16(&lV[db * 64], vt + vbase + (size_t)d * 1024 + kt * 64 + c * 8);
    }
    __syncthreads();
    if (kt * 64 > base_w + 31) continue;       // wave fully below diagonal (uniform)
    // S = Q K^T, both groups share kf
    float4_ S[2][4];
#pragma unroll
    for (int st = 0; st < 4; ++st) {
      float4_ s0 = (float4_){0.f, 0.f, 0.f, 0.f}, s1 = s0;
      int kr = st * 16 + l16;
#pragma unroll
      for (int kc = 0; kc < 4; ++kc) {
        int c = kc * 4 + quad;
        short8 kf = *(const short8a*)&lK[kr * 128 + (c ^ (kr & 15)) * 8];
        s0 = __builtin_amdgcn_mfma_f32_16x16x32_bf16(qf[0][kc], kf, s0, 0, 0, 0);
        s1 = __builtin_amdgcn_mfma_f32_16x16x32_bf16(qf[1][kc], kf, s1, 0, 0, 0);
      }
      S[0][st] = s0; S[1][st] = s1;
    }
    // causal mask + exp + P store
#pragma unroll
    for (int g = 0; g < 2; g++) {
      int gbase = base_w + g * 16;
      if (kt * 64 + 63 > gbase) {
#pragma unroll
        for (int st = 0; st < 4; ++st)
#pragma unroll
          for (int r = 0; r < 4; r++)
            if (kt * 64 + st * 16 + l16 > gbase + quad * 4 + r) S[g][st][r] = -1e30f;
      }
#pragma unroll
      for (int st = 0; st < 4; ++st)
#pragma unroll
        for (int r = 0; r < 4; r++) {
          float pv = __expf(S[g][st][r]);
          rsacc[g][r] += pv;
          lP[wave][(g * 16 + quad * 4 + r) * 72 + st * 16 + l16] = f2b(pv);
        }
    }
    short8 pf[2][2];
#pragma unroll
    for (int g = 0; g < 2; g++)
#pragma unroll
      for (int kc2 = 0; kc2 < 2; kc2++)
        pf[g][kc2] = *(const short8a*)&lP[wave][(g * 16 + l16) * 72 + kc2 * 32 + quad * 8];
#pragma unroll
    for (int dt = 0; dt < 8; ++dt) {
      int d = dt * 16 + l16;
#pragma unroll
      for (int kc2 = 0; kc2 < 2; kc2++) {
        int c = kc2 * 4 + quad;
        short8 vf = *(const short8a*)&lV[d * 64 + (c ^ (d & 7)) * 8];
        O[0][dt] = __builtin_amdgcn_mfma_f32_16x16x32_bf16(pf[0][kc2], vf, O[0][dt], 0, 0, 0);
        O[1][dt] = __builtin_amdgcn_mfma_f32_16x16x32_bf16(pf[1][kc2], vf, O[1][dt], 0, 0, 0);
      }
    }
  }
  float hs = head_scale[h];
#pragma unroll
  for (int g = 0; g < 2; g++) {
    float l_i[4];
#pragma unroll
    for (int r = 0; r < 4; r++) {
      float rs = rsacc[g][r];
#pragma unroll
      for (int off = 8; off; off >>= 1) rs += __shfl_xor(rs, off, 64);
      l_i[r] = rs;
    }
    int qrow = base_w + g * 16 + quad * 4;
#pragma unroll
    for (int dt = 0; dt < 8; ++dt) {
      int col = h * 128 + dt * 16 + l16;
#pragma unroll
      for (int r = 0; r < 4; r++) {
        float o = O[g][dt][r] * (hs / l_i[r]);
        attn[(size_t)(b * 1024 + qrow + r) * 2048 + col] = f2b(o);
      }
    }
  }
}

// ---------- launch ----------
extern "C" void kernel_launch(void* const* d_in, const int* in_sizes, int n_in,
                              void* d_out, int out_size, void* d_ws, size_t ws_size,
                              hipStream_t stream) {
  const float* x  = (const float*)d_in[0];
  const float* Wq = (const float*)d_in[1];
  const float* Wk = (const float*)d_in[2];
  const float* Wv = (const float*)d_in[3];
  const float* Wo = (const float*)d_in[4];
  const float* hs = (const float*)d_in[5];
  float* out = (float*)d_out;
  char* ws = (char*)d_ws;
  // ws layout (64 MB total)
  short* xb    = (short*)(ws);                  // 16 MB  [4096][2048]   (reused as attn)
  short* wqkvt = (short*)(ws + 16777216);       // 12 MB  [3072][2048]
  short* wot   = (short*)(ws + 29360128);       //  8 MB  [2048][2048]
  short* qkv   = (short*)(ws + 37748736);       // 24 MB  [4096][3072] (V cols unused)
  short* vt    = (short*)(ws + 62914560);       //  4 MB  [2048][1024]
  short* attn  = xb;                            // alias: xb dead after GEMM1
  // rope table lives in d_out's tail: d_out (32 MB fp32) is dead until GEMM2 fully overwrites it
  float* rtab  = out + 8257536;                 // 512 KB = 131072 floats

  prep<<<11008, 256, 0, stream>>>(x, Wq, Wk, Wv, Wo, xb, wqkvt, wot, rtab);
  gemm_bt<1, 384><<<dim3(32, 8), 512, 0, stream>>>(xb, wqkvt, (void*)qkv, rtab, vt, 4096, 3072, 2048);
  flash<<<dim3(64, 8), 256, 0, stream>>>(qkv, vt, hs, attn);
  gemm_bt<0, 256><<<dim3(32, 8), 512, 0, stream>>>(attn, wot, (void*)out, nullptr, nullptr, 4096, 2048, 2048);
}